// Round 2
// baseline (135.753 us; speedup 1.0000x reference)
//
#include <hip/hip_runtime.h>
#include <hip/hip_bf16.h>
#include <math.h>

#define N_NODES 4096
#define F_IN    512
#define HID     64
#define H       8
#define NJ      512   // H*HID
#define ALPHA   0.2f

typedef __bf16 bf16x8 __attribute__((ext_vector_type(8)));
typedef float  f32x4  __attribute__((ext_vector_type(4)));

// ---------------------------------------------------------------------------
// Tiled + XOR-pre-swizzled operand layouts (16-B chunk granularity).
//   AhT/AlT: [bm=64][kt=8][unit=512] ; unit u=r*8+c8 holds the 8 bf16 of
//            x[bm*64+r][kt*64 + ((c8 ^ (r&7))*8) .. +8)  (hi / lo split)
//   BthT:    [h=8][kt=8][unit=512]   ; unit u=r*8+c8 holds
//            W[h][kt*64 + (c8^(r&7))*8 + e][r], e=0..7
// The GEMM stages these LINEARLY into LDS via global_load_lds (wave-uniform
// dest + lane*16 — rule 21: swizzle baked into SOURCE, applied again on READ).
// ---------------------------------------------------------------------------
#define A_CHUNKS (N_NODES * F_IN / 8)   // 262144
#define B_CHUNKS (NJ * F_IN / 8)        // 32768

__global__ __launch_bounds__(256) void conv_prep(const float* __restrict__ x,
                                                 const float* __restrict__ W,
                                                 __bf16* __restrict__ AhT,
                                                 __bf16* __restrict__ AlT,
                                                 __bf16* __restrict__ BthT) {
    int id = blockIdx.x * 256 + threadIdx.x;
    if (id < A_CHUNKS) {
        int u  = id & 511;
        int kt = (id >> 9) & 7;
        int bm = id >> 12;
        int r  = u >> 3, c8 = u & 7;
        int col = kt * 64 + ((c8 ^ (r & 7)) << 3);
        const float4* gp = (const float4*)(x + (size_t)(bm * 64 + r) * F_IN + col);
        float4 v0 = gp[0];
        float4 v1 = gp[1];
        float vv[8] = {v0.x, v0.y, v0.z, v0.w, v1.x, v1.y, v1.z, v1.w};
        bf16x8 hv, lv;
        #pragma unroll
        for (int e = 0; e < 8; e++) {
            __bf16 hi = (__bf16)vv[e];
            hv[e] = hi;
            lv[e] = (__bf16)(vv[e] - (float)hi);
        }
        *(bf16x8*)(AhT + (size_t)id * 8) = hv;
        *(bf16x8*)(AlT + (size_t)id * 8) = lv;
    } else {
        int bid = id - A_CHUNKS;
        if (bid < B_CHUNKS) {
            int u  = bid & 511;
            int kt = (bid >> 9) & 7;
            int h  = bid >> 12;
            int r  = u >> 3, c8 = u & 7;
            int kb = kt * 64 + ((c8 ^ (r & 7)) << 3);
            bf16x8 hv;
            #pragma unroll
            for (int e = 0; e < 8; e++) {
                hv[e] = (__bf16)W[((size_t)h * F_IN + kb + e) * HID + r];
            }
            *(bf16x8*)(BthT + (size_t)bid * 8) = hv;
        }
    }
}

// ---------------------------------------------------------------------------
// Kernel 1: Wh GEMM. Zero-VALU staging: global_load_lds(16B) into linear LDS,
// XOR-swizzled ds_read_b128 (lanes 0-7 span all 32 banks -> conflict-free).
// Split-bf16 A (hi+lo MFMA) for fp32-grade accuracy.
// ---------------------------------------------------------------------------
__device__ __forceinline__ void async16(void* lds, const void* g) {
    __builtin_amdgcn_global_load_lds(
        (const __attribute__((address_space(1))) unsigned int*)g,
        (__attribute__((address_space(3))) unsigned int*)lds, 16, 0, 0);
}

__global__ __launch_bounds__(256) void wh_gemm(const __bf16* __restrict__ AhT,
                                               const __bf16* __restrict__ AlT,
                                               const __bf16* __restrict__ BthT,
                                               const float* __restrict__ a,
                                               __bf16* __restrict__ Whb,
                                               float* __restrict__ esrc,
                                               float* __restrict__ edst) {
    const int bid = blockIdx.x;           // 0..511
    const int xcd = bid & 7;              // HW XCD round-robin
    const int s0  = bid >> 3;
    const int bm  = xcd * 8 + (s0 >> 3);  // 8 bm per XCD, heads consecutive
    const int h   = s0 & 7;

    const int tid  = threadIdx.x;
    const int wave = tid >> 6;
    const int lane = tid & 63;
    const int lm = lane & 15;
    const int lq = lane >> 4;

    __shared__ __align__(16) __bf16 smem[3 * 4096];  // Ash | Asl | Bsh (linear 64x64)
    __bf16* Ash = smem;
    __bf16* Asl = smem + 4096;
    __bf16* Bsh = smem + 8192;

    f32x4 acc[4];
    #pragma unroll
    for (int c = 0; c < 4; c++) acc[c] = (f32x4){0.f, 0.f, 0.f, 0.f};

    const __bf16* tA_h = AhT  + (size_t)bm * (8 * 4096);
    const __bf16* tA_l = AlT  + (size_t)bm * (8 * 4096);
    const __bf16* tB   = BthT + (size_t)h  * (8 * 4096);

    const int rowA = wave * 16 + lm;

    for (int kt = 0; kt < 8; kt++) {
        const size_t ko = (size_t)kt * 4096;
        #pragma unroll
        for (int s = 0; s < 2; s++) {
            int u  = s * 256 + tid;             // per-lane unit (0..511)
            int ub = s * 256 + wave * 64;       // wave-uniform LDS unit base
            async16(Ash + ub * 8, tA_h + ko + (size_t)u * 8);
            async16(Asl + ub * 8, tA_l + ko + (size_t)u * 8);
            async16(Bsh + ub * 8, tB   + ko + (size_t)u * 8);
        }
        __syncthreads();   // compiler drains vmcnt before s_barrier

        #pragma unroll
        for (int kh = 0; kh < 2; kh++) {
            const int ce = (((kh << 2) + lq) ^ (lm & 7)) << 3;  // swizzled elem off
            bf16x8 afh = *(const bf16x8*)&Ash[rowA * 64 + ce];
            bf16x8 afl = *(const bf16x8*)&Asl[rowA * 64 + ce];
            bf16x8 bh[4];
            #pragma unroll
            for (int c = 0; c < 4; c++) {
                bh[c] = *(const bf16x8*)&Bsh[(c * 16 + lm) * 64 + ce];
            }
            #pragma unroll
            for (int c = 0; c < 4; c++) {
                acc[c] = __builtin_amdgcn_mfma_f32_16x16x32_bf16(afh, bh[c], acc[c], 0, 0, 0);
                acc[c] = __builtin_amdgcn_mfma_f32_16x16x32_bf16(afl, bh[c], acc[c], 0, 0, 0);
            }
        }
        __syncthreads();
    }

    float a1c[4], a2c[4];
    #pragma unroll
    for (int c = 0; c < 4; c++) {
        a1c[c] = a[h * 2 * HID + c * 16 + lm];
        a2c[c] = a[h * 2 * HID + HID + c * 16 + lm];
    }

    #pragma unroll
    for (int r = 0; r < 4; r++) {
        int row = bm * 64 + wave * 16 + lq * 4 + r;
        float s1 = 0.f, s2 = 0.f;
        #pragma unroll
        for (int c = 0; c < 4; c++) {
            float v = acc[c][r];
            Whb[(size_t)row * NJ + h * HID + c * 16 + lm] = (__bf16)v;
            s1 += v * a1c[c];
            s2 += v * a2c[c];
        }
        #pragma unroll
        for (int o = 1; o < 16; o <<= 1) {
            s1 += __shfl_xor(s1, o);
            s2 += __shfl_xor(s2, o);
        }
        if (lm == 0) {
            esrc[h * N_NODES + row] = s1;
            edst[h * N_NODES + row] = s2;
        }
    }
}

// ---------------- Kernel 2: monolithic gat_attn, 256 threads / row -------------
#define MAXN 128

__global__ __launch_bounds__(256) void gat_attn(const float* __restrict__ adj,
                                                const __bf16* __restrict__ Whb,
                                                const float* __restrict__ esrc,
                                                const float* __restrict__ edst,
                                                float* __restrict__ out) {
    const int i    = blockIdx.x;
    const int tid  = threadIdx.x;
    const int wave = tid >> 6;
    const int lane = tid & 63;
    __shared__ int    nbr[MAXN];
    __shared__ __align__(8)  float2 an[H][MAXN + 4];
    __shared__ float  denom[H];
    __shared__ __align__(16) f32x4 part[3][2][64];
    __shared__ int    cnt;

    if (tid == 0) cnt = 0;
    __syncthreads();

    // phase 1: batched ballot compaction; adj streamed nontemporal (keep L2 for Whb)
    const unsigned long long lt = (1ull << lane) - 1ull;
    const f32x4* arow = (const f32x4*)(adj + (size_t)i * N_NODES);
    f32x4 q[4];
    #pragma unroll
    for (int cc = 0; cc < 4; cc++) q[cc] = __builtin_nontemporal_load(arow + cc * 256 + tid);
    #pragma unroll
    for (int cc = 0; cc < 4; cc++) {
        unsigned long long b0 = __ballot(q[cc][0] > 0.f);
        unsigned long long b1 = __ballot(q[cc][1] > 0.f);
        unsigned long long b2 = __ballot(q[cc][2] > 0.f);
        unsigned long long b3 = __ballot(q[cc][3] > 0.f);
        int c0 = __popcll(b0), c1 = __popcll(b1), c2 = __popcll(b2), c3 = __popcll(b3);
        int base = 0;
        if (lane == 0) base = atomicAdd(&cnt, c0 + c1 + c2 + c3);
        base = __shfl(base, 0);
        int col = (cc * 256 + tid) * 4;
        if (q[cc][0] > 0.f) nbr[base + __popcll(b0 & lt)] = col;
        base += c0;
        if (q[cc][1] > 0.f) nbr[base + __popcll(b1 & lt)] = col + 1;
        base += c1;
        if (q[cc][2] > 0.f) nbr[base + __popcll(b2 & lt)] = col + 2;
        base += c2;
        if (q[cc][3] > 0.f) nbr[base + __popcll(b3 & lt)] = col + 3;
    }
    __syncthreads();
    const int n = cnt;

    // phase 2: wave serves heads {2*wave, 2*wave+1}
    #pragma unroll
    for (int k = 0; k < 2; k++) {
        const int hh = wave * 2 + k;
        float es = esrc[hh * N_NODES + i];
        float m = -1e30f;
        for (int j = lane; j < n; j += 64) {
            int c = nbr[j];
            float lg = es + edst[hh * N_NODES + c];
            lg = lg > 0.f ? lg : ALPHA * lg;
            an[hh][j] = make_float2(lg, __int_as_float(c << 10));
            m = fmaxf(m, lg);
        }
        #pragma unroll
        for (int o = 32; o; o >>= 1) m = fmaxf(m, __shfl_xor(m, o));
        float s = 0.f;
        for (int j = lane; j < n; j += 64) {
            float w = __expf(an[hh][j].x - m);
            an[hh][j].x = w;
            s += w;
        }
        #pragma unroll
        for (int o = 32; o; o >>= 1) s += __shfl_xor(s, o);
        if (lane == 0) denom[hh] = s;
    }
    __syncthreads();

    // phase 3: 4 j-streams x 64 dim-threads, uint4 (16B) gathers
    const int qd = tid >> 6;          // 0..3: handles j ≡ qd (mod 4)
    const int t  = tid & 63;          // dim-octet: dims [t*8, t*8+7]
    const int h  = t >> 3;
    const char* wp = (const char*)Whb + t * 16;
    float a0 = 0.f, a1 = 0.f, a2 = 0.f, a3 = 0.f;
    float a4 = 0.f, a5 = 0.f, a6 = 0.f, a7 = 0.f;
    #pragma unroll 4
    for (int j = qd; j < n; j += 4) {
        float2 p = an[h][j];
        uint4 u = *(const uint4*)(wp + __float_as_uint(p.y));
        float w = p.x;
        a0 += w * __uint_as_float(u.x << 16);
        a1 += w * __uint_as_float(u.x & 0xffff0000u);
        a2 += w * __uint_as_float(u.y << 16);
        a3 += w * __uint_as_float(u.y & 0xffff0000u);
        a4 += w * __uint_as_float(u.z << 16);
        a5 += w * __uint_as_float(u.z & 0xffff0000u);
        a6 += w * __uint_as_float(u.w << 16);
        a7 += w * __uint_as_float(u.w & 0xffff0000u);
    }
    if (qd) {
        part[qd - 1][0][t] = (f32x4){a0, a1, a2, a3};
        part[qd - 1][1][t] = (f32x4){a4, a5, a6, a7};
    }
    __syncthreads();
    if (qd == 0) {
        f32x4 r0 = (f32x4){a0, a1, a2, a3};
        f32x4 r1 = (f32x4){a4, a5, a6, a7};
        #pragma unroll
        for (int s = 0; s < 3; s++) {
            r0 += part[s][0][t];
            r1 += part[s][1][t];
        }
        float inv = 1.f / denom[h];
        float b[8];
        #pragma unroll
        for (int e = 0; e < 4; e++) b[e] = r0[e] * inv;
        #pragma unroll
        for (int e = 0; e < 4; e++) b[4 + e] = r1[e] * inv;
        #pragma unroll
        for (int e = 0; e < 8; e++) b[e] = b[e] > 0.f ? b[e] : expm1f(b[e]);
        f32x4 o0 = (f32x4){b[0], b[1], b[2], b[3]};
        f32x4 o1 = (f32x4){b[4], b[5], b[6], b[7]};
        f32x4* op = (f32x4*)(out + (size_t)i * NJ + t * 8);
        __builtin_nontemporal_store(o0, op);
        __builtin_nontemporal_store(o1, op + 1);
    }
}

extern "C" void kernel_launch(void* const* d_in, const int* in_sizes, int n_in,
                              void* d_out, int out_size, void* d_ws, size_t ws_size,
                              hipStream_t stream) {
    const float* x   = (const float*)d_in[0];   // [N, F_IN]
    const float* adj = (const float*)d_in[1];   // [N, N]
    const float* W   = (const float*)d_in[2];   // [H, F_IN, HID]
    const float* a   = (const float*)d_in[3];   // [H, 2*HID]
    float* out = (float*)d_out;                 // [N, H*HID]

    float*  esrc = (float*)d_ws;                              // H*N floats
    float*  edst = esrc + (size_t)H * N_NODES;
    __bf16* Whb  = (__bf16*)(edst + (size_t)H * N_NODES);     // 4 MB
    __bf16* AhT  = Whb + (size_t)N_NODES * NJ;                // 4 MB (tiled-swizzled)
    __bf16* AlT  = AhT + (size_t)N_NODES * F_IN;              // 4 MB
    __bf16* BthT = AlT + (size_t)N_NODES * F_IN;              // 512 KB

    conv_prep<<<(A_CHUNKS + B_CHUNKS) / 256, 256, 0, stream>>>(x, W, AhT, AlT, BthT);

    wh_gemm<<<512, 256, 0, stream>>>(AhT, AlT, BthT, a, Whb, esrc, edst);

    gat_attn<<<N_NODES, 256, 0, stream>>>(adj, Whb, esrc, edst, out);
}

// Round 3
// 129.332 us; speedup vs baseline: 1.0497x; 1.0497x over previous
//
#include <hip/hip_runtime.h>
#include <hip/hip_bf16.h>
#include <math.h>

#define N_NODES 4096
#define F_IN    512
#define HID     64
#define H       8
#define NJ      512   // H*HID
#define ALPHA   0.2f

typedef __bf16 bf16x8 __attribute__((ext_vector_type(8)));
typedef float  f32x4  __attribute__((ext_vector_type(4)));

// ---------------------------------------------------------------------------
// Tiled + XOR-pre-swizzled operand layouts (16-B chunk granularity).
//   AhT/AlT: [bm=64][kt=8][unit=512] ; unit u=r*8+c8 holds the 8 bf16 of
//            x[bm*64+r][kt*64 + ((c8 ^ (r&7))*8) .. +8)  (hi / lo split)
//   BthT:    [h=8][kt=8][unit=512]   ; unit u=r*8+c8 holds
//            W[h][kt*64 + (c8^(r&7))*8 + e][r], e=0..7
// GEMM stages these LINEARLY into LDS via global_load_lds (swizzle baked into
// the SOURCE, applied again on the LDS READ — rule 21 both-sides-or-neither).
// ---------------------------------------------------------------------------
#define A_CHUNKS (N_NODES * F_IN / 8)   // 262144
#define B_CHUNKS (NJ * F_IN / 8)        // 32768

__global__ __launch_bounds__(256) void conv_prep(const float* __restrict__ x,
                                                 const float* __restrict__ W,
                                                 __bf16* __restrict__ AhT,
                                                 __bf16* __restrict__ AlT,
                                                 __bf16* __restrict__ BthT) {
    int id = blockIdx.x * 256 + threadIdx.x;
    if (id < A_CHUNKS) {
        int u  = id & 511;
        int kt = (id >> 9) & 7;
        int bm = id >> 12;
        int r  = u >> 3, c8 = u & 7;
        int col = kt * 64 + ((c8 ^ (r & 7)) << 3);
        const float4* gp = (const float4*)(x + (size_t)(bm * 64 + r) * F_IN + col);
        float4 v0 = gp[0];
        float4 v1 = gp[1];
        float vv[8] = {v0.x, v0.y, v0.z, v0.w, v1.x, v1.y, v1.z, v1.w};
        bf16x8 hv, lv;
        #pragma unroll
        for (int e = 0; e < 8; e++) {
            __bf16 hi = (__bf16)vv[e];
            hv[e] = hi;
            lv[e] = (__bf16)(vv[e] - (float)hi);
        }
        *(bf16x8*)(AhT + (size_t)id * 8) = hv;
        *(bf16x8*)(AlT + (size_t)id * 8) = lv;
    } else {
        int bid = id - A_CHUNKS;
        if (bid < B_CHUNKS) {
            int u  = bid & 511;
            int kt = (bid >> 9) & 7;
            int h  = bid >> 12;
            int r  = u >> 3, c8 = u & 7;
            int kb = kt * 64 + ((c8 ^ (r & 7)) << 3);
            bf16x8 hv;
            #pragma unroll
            for (int e = 0; e < 8; e++) {
                hv[e] = (__bf16)W[((size_t)h * F_IN + kb + e) * HID + r];
            }
            *(bf16x8*)(BthT + (size_t)bid * 8) = hv;
        }
    }
}

// ---------------------------------------------------------------------------
// Kernel 1: Wh GEMM — T3 2-phase double-buffered pipeline with counted vmcnt.
// STAGE(next) issued BEFORE compute(cur); raw s_barrier + s_waitcnt vmcnt(6)
// keeps the next tile's 6 loads in flight across the barrier (no vmcnt(0)
// drain in the main loop — the m97-structure stall this removes).
// ---------------------------------------------------------------------------
__device__ __forceinline__ void async16(void* lds, const void* g) {
    __builtin_amdgcn_global_load_lds(
        (const __attribute__((address_space(1))) unsigned int*)g,
        (__attribute__((address_space(3))) unsigned int*)lds, 16, 0, 0);
}

__global__ __launch_bounds__(256) void wh_gemm(const __bf16* __restrict__ AhT,
                                               const __bf16* __restrict__ AlT,
                                               const __bf16* __restrict__ BthT,
                                               const float* __restrict__ a,
                                               __bf16* __restrict__ Whb,
                                               float* __restrict__ esrc,
                                               float* __restrict__ edst) {
    const int bid = blockIdx.x;           // 0..511
    const int xcd = bid & 7;              // HW XCD round-robin
    const int s0  = bid >> 3;
    const int bm  = xcd * 8 + (s0 >> 3);  // 8 bm per XCD, heads consecutive
    const int h   = s0 & 7;

    const int tid  = threadIdx.x;
    const int wave = tid >> 6;
    const int lane = tid & 63;
    const int lm = lane & 15;
    const int lq = lane >> 4;

    // double buffer: [buf][Ash 4096 | Asl 4096 | Bsh 4096]
    __shared__ __align__(16) __bf16 smem[2 * 3 * 4096];

    f32x4 acc[4];
    #pragma unroll
    for (int c = 0; c < 4; c++) acc[c] = (f32x4){0.f, 0.f, 0.f, 0.f};

    const __bf16* tA_h = AhT  + (size_t)bm * (8 * 4096);
    const __bf16* tA_l = AlT  + (size_t)bm * (8 * 4096);
    const __bf16* tB   = BthT + (size_t)h  * (8 * 4096);

    const int rowA = wave * 16 + lm;

    auto stage = [&](int buf, int kt2) {
        __bf16* base = smem + buf * 12288;
        const size_t ko = (size_t)kt2 * 4096;
        #pragma unroll
        for (int s = 0; s < 2; s++) {
            int u  = s * 256 + tid;             // per-lane unit (0..511)
            int ub = s * 256 + wave * 64;       // wave-uniform LDS unit base
            async16(base +        ub * 8, tA_h + ko + (size_t)u * 8);
            async16(base + 4096 + ub * 8, tA_l + ko + (size_t)u * 8);
            async16(base + 8192 + ub * 8, tB   + ko + (size_t)u * 8);
        }
    };

    stage(0, 0);   // prologue

    for (int kt = 0; kt < 8; kt++) {
        const int cur = kt & 1;
        if (kt < 7) {
            stage(1 - cur, kt + 1);   // issue next tile's 6 loads (stay in flight)
            asm volatile("s_waitcnt vmcnt(6)" ::: "memory");   // cur's 6 done
        } else {
            asm volatile("s_waitcnt vmcnt(0)" ::: "memory");
        }
        __builtin_amdgcn_s_barrier();
        __builtin_amdgcn_sched_barrier(0);

        const __bf16* Ash = smem + cur * 12288;
        const __bf16* Asl = Ash + 4096;
        const __bf16* Bsh = Ash + 8192;

        #pragma unroll
        for (int kh = 0; kh < 2; kh++) {
            const int ce = (((kh << 2) + lq) ^ (lm & 7)) << 3;  // swizzled elem off
            bf16x8 afh = *(const bf16x8*)&Ash[rowA * 64 + ce];
            bf16x8 afl = *(const bf16x8*)&Asl[rowA * 64 + ce];
            bf16x8 bh[4];
            #pragma unroll
            for (int c = 0; c < 4; c++) {
                bh[c] = *(const bf16x8*)&Bsh[(c * 16 + lm) * 64 + ce];
            }
            #pragma unroll
            for (int c = 0; c < 4; c++) {
                acc[c] = __builtin_amdgcn_mfma_f32_16x16x32_bf16(afh, bh[c], acc[c], 0, 0, 0);
                acc[c] = __builtin_amdgcn_mfma_f32_16x16x32_bf16(afl, bh[c], acc[c], 0, 0, 0);
            }
        }
        __builtin_amdgcn_s_barrier();   // all waves done reading buf[cur]
    }

    float a1c[4], a2c[4];
    #pragma unroll
    for (int c = 0; c < 4; c++) {
        a1c[c] = a[h * 2 * HID + c * 16 + lm];
        a2c[c] = a[h * 2 * HID + HID + c * 16 + lm];
    }

    #pragma unroll
    for (int r = 0; r < 4; r++) {
        int row = bm * 64 + wave * 16 + lq * 4 + r;
        float s1 = 0.f, s2 = 0.f;
        #pragma unroll
        for (int c = 0; c < 4; c++) {
            float v = acc[c][r];
            Whb[(size_t)row * NJ + h * HID + c * 16 + lm] = (__bf16)v;
            s1 += v * a1c[c];
            s2 += v * a2c[c];
        }
        #pragma unroll
        for (int o = 1; o < 16; o <<= 1) {
            s1 += __shfl_xor(s1, o);
            s2 += __shfl_xor(s2, o);
        }
        if (lm == 0) {
            esrc[h * N_NODES + row] = s1;
            edst[h * N_NODES + row] = s2;
        }
    }
}

// ---------------- Kernel 2: gat_attn — exact round-0 (fastest) body -----------
#define MAXN 128

__global__ __launch_bounds__(256) void gat_attn(const float* __restrict__ adj,
                                                const __bf16* __restrict__ Whb,
                                                const float* __restrict__ esrc,
                                                const float* __restrict__ edst,
                                                float* __restrict__ out) {
    const int i    = blockIdx.x;
    const int tid  = threadIdx.x;
    const int wave = tid >> 6;
    const int lane = tid & 63;
    __shared__ int    nbr[MAXN];
    __shared__ __align__(8)  float2 an[H][MAXN];  // .x=att  .y=asfloat(row byte off)
    __shared__ float  denom[H];
    __shared__ __align__(16) float4 part[128];
    __shared__ int    cnt;

    if (tid == 0) cnt = 0;
    __syncthreads();

    // phase 1: batched ballot compaction; 4 chunks of 1024 elems, loads hoisted
    const unsigned long long lt = (1ull << lane) - 1ull;
    const float4* arow = (const float4*)(adj + (size_t)i * N_NODES);
    float4 q[4];
    #pragma unroll
    for (int cc = 0; cc < 4; cc++) q[cc] = arow[cc * 256 + tid];
    #pragma unroll
    for (int cc = 0; cc < 4; cc++) {
        unsigned long long b0 = __ballot(q[cc].x > 0.f);
        unsigned long long b1 = __ballot(q[cc].y > 0.f);
        unsigned long long b2 = __ballot(q[cc].z > 0.f);
        unsigned long long b3 = __ballot(q[cc].w > 0.f);
        int c0 = __popcll(b0), c1 = __popcll(b1), c2 = __popcll(b2), c3 = __popcll(b3);
        int base = 0;
        if (lane == 0) base = atomicAdd(&cnt, c0 + c1 + c2 + c3);
        base = __shfl(base, 0);
        int col = (cc * 256 + tid) * 4;
        if (q[cc].x > 0.f) nbr[base + __popcll(b0 & lt)] = col;
        base += c0;
        if (q[cc].y > 0.f) nbr[base + __popcll(b1 & lt)] = col + 1;
        base += c1;
        if (q[cc].z > 0.f) nbr[base + __popcll(b2 & lt)] = col + 2;
        base += c2;
        if (q[cc].w > 0.f) nbr[base + __popcll(b3 & lt)] = col + 3;
    }
    __syncthreads();
    const int n = cnt;

    // phase 2: wave serves heads {2*wave, 2*wave+1}
    #pragma unroll
    for (int k = 0; k < 2; k++) {
        const int h = wave * 2 + k;
        float es = esrc[h * N_NODES + i];
        float m = -1e30f;
        for (int j = lane; j < n; j += 64) {
            int c = nbr[j];
            float lg = es + edst[h * N_NODES + c];
            lg = lg > 0.f ? lg : ALPHA * lg;
            an[h][j] = make_float2(lg, __int_as_float(c << 10));
            m = fmaxf(m, lg);
        }
        #pragma unroll
        for (int o = 32; o; o >>= 1) m = fmaxf(m, __shfl_xor(m, o));
        float s = 0.f;
        for (int j = lane; j < n; j += 64) {
            float w = __expf(an[h][j].x - m);
            an[h][j].x = w;
            s += w;
        }
        #pragma unroll
        for (int o = 32; o; o >>= 1) s += __shfl_xor(s, o);
        if (lane == 0) denom[h] = s;
    }
    __syncthreads();

    // phase 3: half-split gather — 2 j-streams, dwordx2 per thread, unroll 4
    const int qd = tid >> 7;          // 0..1: handles j ≡ qd (mod 2)
    const int t  = tid & 127;         // dim-quad: dims [t*4, t*4+3]
    const int h  = t >> 4;
    const char* wp = (const char*)Whb + t * 8;
    float a0 = 0.f, a1 = 0.f, a2 = 0.f, a3 = 0.f;
    #pragma unroll 4
    for (int j = qd; j < n; j += 2) {
        float2 p = an[h][j];
        uint2 u = *(const uint2*)(wp + __float_as_uint(p.y));
        float w = p.x;
        a0 += w * __uint_as_float(u.x << 16);
        a1 += w * __uint_as_float(u.x & 0xffff0000u);
        a2 += w * __uint_as_float(u.y << 16);
        a3 += w * __uint_as_float(u.y & 0xffff0000u);
    }
    if (qd) part[t] = make_float4(a0, a1, a2, a3);
    __syncthreads();
    if (qd == 0) {
        float4 p = part[t];
        a0 += p.x; a1 += p.y; a2 += p.z; a3 += p.w;
        float inv = 1.f / denom[h];
        a0 *= inv; a1 *= inv; a2 *= inv; a3 *= inv;
        a0 = a0 > 0.f ? a0 : expm1f(a0);
        a1 = a1 > 0.f ? a1 : expm1f(a1);
        a2 = a2 > 0.f ? a2 : expm1f(a2);
        a3 = a3 > 0.f ? a3 : expm1f(a3);
        *(float4*)(out + (size_t)i * NJ + t * 4) = make_float4(a0, a1, a2, a3);
    }
}

extern "C" void kernel_launch(void* const* d_in, const int* in_sizes, int n_in,
                              void* d_out, int out_size, void* d_ws, size_t ws_size,
                              hipStream_t stream) {
    const float* x   = (const float*)d_in[0];   // [N, F_IN]
    const float* adj = (const float*)d_in[1];   // [N, N]
    const float* W   = (const float*)d_in[2];   // [H, F_IN, HID]
    const float* a   = (const float*)d_in[3];   // [H, 2*HID]
    float* out = (float*)d_out;                 // [N, H*HID]

    float*  esrc = (float*)d_ws;                              // H*N floats
    float*  edst = esrc + (size_t)H * N_NODES;
    __bf16* Whb  = (__bf16*)(edst + (size_t)H * N_NODES);     // 4 MB
    __bf16* AhT  = Whb + (size_t)N_NODES * NJ;                // 4 MB (tiled-swizzled)
    __bf16* AlT  = AhT + (size_t)N_NODES * F_IN;              // 4 MB
    __bf16* BthT = AlT + (size_t)N_NODES * F_IN;              // 512 KB

    conv_prep<<<(A_CHUNKS + B_CHUNKS) / 256, 256, 0, stream>>>(x, W, AhT, AlT, BthT);

    wh_gemm<<<512, 256, 0, stream>>>(AhT, AlT, BthT, a, Whb, esrc, edst);

    gat_attn<<<N_NODES, 256, 0, stream>>>(adj, Whb, esrc, edst, out);
}